// Round 2
// 206.246 us; speedup vs baseline: 1.1101x; 1.1101x over previous
//
#include <hip/hip_runtime.h>

// Problem constants
#define NP 2048          // B*H1*W1 points
#define CD 768           // channels
#define NSPLIT 6         // channel splits for d2 partials (128 ch each)
#define NJOBS 528        // 136 XX-tri + 136 YY-tri + 256 XY tiles
#define MMD_GAMMA 0.00065f

typedef short bf16frag __attribute__((ext_vector_type(8)));
typedef float f32x4 __attribute__((ext_vector_type(4)));

#define GLD16(g, l)  __builtin_amdgcn_global_load_lds(                      \
    (const __attribute__((address_space(1))) void*)(g),                     \
    (__attribute__((address_space(3))) void*)(l), 16, 0, 0)

static __device__ inline unsigned short f2bf(float v) {
    union { float f; unsigned u; } a; a.f = v;
    unsigned r = a.u + 0x7fffu + ((a.u >> 16) & 1u);
    return (unsigned short)(r >> 16);
}

// ---------------------------------------------------------------------------
// Fused prep: blocks 0..1535 = d2 partials (memory-heavy, scheduled first);
// blocks 1536..2303 = x transpose + bf16 pack + a2 partial norms.
// Branches are independent (disjoint outputs) -> true in-stream overlap.
// d2/argmax path stays f64 and is byte-identical to the passing version.
__global__ __launch_bounds__(256, 4)
void k_prep(const float* __restrict__ x, const float* __restrict__ y,
            double* __restrict__ d2p,
            unsigned short* __restrict__ Xhi,
            float* __restrict__ a2f) {
    __shared__ double redd[8][32][4];     // d2 branch (8 KB)
    __shared__ float tile[64][33];        // transpose branch (8.4 KB)
    __shared__ float sqred[8][32];
    int bid = blockIdx.x;
    int tid = threadIdx.x;

    if (bid < 1536) {
        // ---- d2 partial branch (identical math/order to passing kernel) ----
        int bxh = bid & 255;
        int cs  = bid >> 8;
        int b = bxh >> 7, h = bxh & 127;
        int h1 = h >> 2, i = h & 3;
        int w1 = tid & 31, cg = tid >> 5;
        int c0 = cs * 128 + cg;
        const float* yp = y + ((size_t)(b * 768 + c0) * 128 + h) * 128 + 4 * w1;
        const float* xp = x + (size_t)(b * 768 + c0) * 1024 + h1 * 32 + w1;
        double a0 = 0.0, a1 = 0.0, a2 = 0.0, a3 = 0.0;
        #pragma unroll 8
        for (int k = 0; k < 16; ++k) {
            float4 yv = *(const float4*)yp;
            float xv = *xp;
            double xd = (double)xv;
            double d0 = xd - (double)yv.x;
            double d1 = xd - (double)yv.y;
            double d2_ = xd - (double)yv.z;
            double d3 = xd - (double)yv.w;
            a0 += d0 * d0; a1 += d1 * d1; a2 += d2_ * d2_; a3 += d3 * d3;
            yp += (size_t)8 * 16384;
            xp += (size_t)8 * 1024;
        }
        redd[cg][w1][0] = a0; redd[cg][w1][1] = a1;
        redd[cg][w1][2] = a2; redd[cg][w1][3] = a3;
        __syncthreads();
        if (tid < 128) {
            int w = tid >> 2, j = tid & 3;
            double s = 0.0;
            #pragma unroll
            for (int g = 0; g < 8; ++g) s += redd[g][w][j];
            int n = b * 1024 + h1 * 32 + w;
            d2p[((size_t)cs * NP + n) * 16 + i * 4 + j] = s;
        }
    } else {
        // ---- transpose + pack branch (lo residual removed: dead with 1-term Gram) ----
        int id = bid - 1536;
        int bx = id & 63;
        int c0 = (id >> 6) * 64;
        int b = bx >> 5, h1 = bx & 31;
        const float* src = x + (size_t)(b * 768 + c0) * 1024 + h1 * 32;
        #pragma unroll
        for (int p = 0; p < 8; ++p) {
            int cl = p * 8 + (tid >> 5);
            int w1 = tid & 31;
            tile[cl][w1] = src[(size_t)cl * 1024 + w1];
        }
        __syncthreads();
        int n0 = bx * 32;
        #pragma unroll
        for (int p = 0; p < 8; ++p) {
            int w1 = p * 4 + (tid >> 6);
            int c  = tid & 63;
            float v = tile[c][w1];
            size_t o = (size_t)(n0 + w1) * CD + c0 + c;
            Xhi[o] = f2bf(v);
        }
        {
            int w1 = tid & 31, cseg = tid >> 5;
            float s = 0.f;
            #pragma unroll
            for (int u = 0; u < 8; ++u) {
                float v = tile[cseg * 8 + u][w1];
                s += v * v;
            }
            sqred[cseg][w1] = s;
        }
        __syncthreads();
        if (tid < 32) {
            float s = 0.f;
            #pragma unroll
            for (int g = 0; g < 8; ++g) s += sqred[g][tid];
            atomicAdd(&a2f[n0 + tid], s);
        }
    }
}

// ---------------------------------------------------------------------------
// Fused argmax + coalesced gather + bf16 pack + b2 partial norms.
__global__ __launch_bounds__(256, 4)
void k_gather_pack_y(const float* __restrict__ y, const double* __restrict__ d2p,
                     unsigned short* __restrict__ Yhi,
                     float* __restrict__ b2f) {
    __shared__ float ytile[8][520];
    __shared__ int sOff[32];
    __shared__ float sqred[32][8];
    int bh = blockIdx.x;                // b*32 + h1
    int cs = blockIdx.y;                // 0..11, 64 channels each
    int b = bh >> 5, h1 = bh & 31;
    int tid = threadIdx.x;
    if (tid < 32) {
        int n = b * 1024 + h1 * 32 + tid;
        double s[16];
        #pragma unroll
        for (int k = 0; k < 16; ++k) s[k] = 0.0;
        for (int c = 0; c < NSPLIT; ++c) {
            #pragma unroll
            for (int k = 0; k < 16; ++k) s[k] += d2p[((size_t)c * NP + n) * 16 + k];
        }
        double best = s[0]; int bi = 0;
        #pragma unroll
        for (int k = 1; k < 16; ++k) if (s[k] > best) { best = s[k]; bi = k; }
        sOff[tid] = (bi >> 2) * 128 + 4 * tid + (bi & 3);
    }
    __syncthreads();
    int c_loc = tid & 7, n_loc = tid >> 3;
    int ch_s = tid >> 5, part = tid & 31;
    int off = sOff[n_loc];
    int n = b * 1024 + h1 * 32 + n_loc;
    float sq = 0.f;
    for (int kt = 0; kt < 8; ++kt) {
        int c0 = cs * 64 + kt * 8;
        __syncthreads();
        const float* src = y + ((size_t)(b * 768 + c0 + ch_s) * 128 + 4 * h1) * 128;
        #pragma unroll
        for (int u = 0; u < 4; ++u)
            *(float4*)&ytile[ch_s][u * 128 + part * 4] = *(const float4*)(src + u * 128 + part * 4);
        __syncthreads();
        float v = ytile[c_loc][off];
        unsigned short h = f2bf(v);
        size_t o = (size_t)n * CD + c0 + c_loc;
        Yhi[o] = h;
        sq += v * v;
    }
    sqred[n_loc][c_loc] = sq;
    __syncthreads();
    if (tid < 32) {
        float s = 0.f;
        #pragma unroll
        for (int g = 0; g < 8; ++g) s += sqred[tid][g];
        atomicAdd(&b2f[b * 1024 + h1 * 32 + tid], s);
    }
}

// ---------------------------------------------------------------------------
// MFMA Gram + exp-sum, 1-term (Gram = a_hi . b_hi): the B side was bf16-
// truncated in the 2-term version anyway, so per-entry error only grows by
// sqrt(2) while MFMA count, A-staging bytes, and barrier crossings all halve.
// K=768 as 12 windows of K=64; both operands use the verified XOR-(r&7)
// swizzle on 64-short (128 B) rows. Embedded finalize via done-counter.
__global__ __launch_bounds__(256, 3)
void k_mmd_mfma(const unsigned short* __restrict__ Xhi,
                const unsigned short* __restrict__ Yhi,
                const float* __restrict__ a2, const float* __restrict__ b2,
                double* __restrict__ accg, unsigned int* __restrict__ done,
                float* __restrict__ out) {
    __shared__ unsigned short As[128 * 64];   // 16 KB
    __shared__ unsigned short Bs[128 * 64];   // 16 KB
    __shared__ float red[256];

    int id = blockIdx.x;
    int z, bx, by;
    double w = 1.0;
    if (id < 272) {
        z = (id < 136) ? 0 : 1;
        if (id >= 136) id -= 136;
        int r = 0;
        while (id >= 16 - r) { id -= 16 - r; ++r; }
        by = r; bx = r + id;
        if (bx != by) w = 2.0;
    } else {
        z = 2; id -= 272;
        bx = id & 15; by = id >> 4;
    }
    const unsigned short* AH = (z == 1) ? Yhi : Xhi;
    const unsigned short* BH = (z == 0) ? Xhi : Yhi;
    const float* na = (z == 1) ? b2 : a2;
    const float* nb = (z == 0) ? a2 : b2;
    int i0 = by * 128, j0 = bx * 128;

    int tid = threadIdx.x;
    int lane = tid & 63;
    int wv = tid >> 6;
    int wr = wv >> 1, wc = wv & 1;
    int m = lane & 15, q = lane >> 4;
    int lrow = lane >> 3, lchunk = lane & 7;   // staging: 8 rows x 8 chunks/wave

    f32x4 acc[4][4] = {};

    for (int wnd = 0; wnd < 12; ++wnd) {
        int c0 = wnd * 64;
        __syncthreads();
        #pragma unroll
        for (int s = 0; s < 4; ++s) {
            int r0 = s * 32 + wv * 8;
            int r  = r0 + lrow;
            int cg = lchunk ^ (r & 7);
            GLD16(AH + (size_t)(i0 + r) * CD + c0 + cg * 8, &As[r0 * 64]);
        }
        #pragma unroll
        for (int s = 0; s < 4; ++s) {
            int r0 = s * 32 + wv * 8;
            int r  = r0 + lrow;
            int cg = lchunk ^ (r & 7);
            GLD16(BH + (size_t)(j0 + r) * CD + c0 + cg * 8, &Bs[r0 * 64]);
        }
        __syncthreads();
        #pragma unroll
        for (int kh = 0; kh < 2; ++kh) {      // two K=32 halves of the window
            bf16frag af[4], bg[4];
            #pragma unroll
            for (int t = 0; t < 4; ++t) {
                int ra = wr * 64 + t * 16 + m;
                af[t] = *(const bf16frag*)&As[ra * 64 + ((kh * 4 + q) ^ (ra & 7)) * 8];
            }
            #pragma unroll
            for (int t = 0; t < 4; ++t) {
                int rb = wc * 64 + t * 16 + m;
                bg[t] = *(const bf16frag*)&Bs[rb * 64 + ((kh * 4 + q) ^ (rb & 7)) * 8];
            }
            #pragma unroll
            for (int ti = 0; ti < 4; ++ti)
                #pragma unroll
                for (int tj = 0; tj < 4; ++tj)
                    acc[ti][tj] = __builtin_amdgcn_mfma_f32_16x16x32_bf16(
                        af[ti], bg[tj], acc[ti][tj], 0, 0, 0);
        }
    }

    float s = 0.0f;
    #pragma unroll
    for (int ti = 0; ti < 4; ++ti) {
        #pragma unroll
        for (int r = 0; r < 4; ++r) {
            int i = i0 + wr * 64 + ti * 16 + q * 4 + r;
            float ai = na[i];
            #pragma unroll
            for (int tj = 0; tj < 4; ++tj) {
                int j = j0 + wc * 64 + tj * 16 + m;
                float d = ai + nb[j] - 2.0f * acc[ti][tj][r];
                d = fmaxf(d, 0.0f);
                s += expf(-MMD_GAMMA * d);
            }
        }
    }
    red[tid] = s;
    __syncthreads();
    for (int st = 128; st > 0; st >>= 1) {
        if (tid < st) red[tid] += red[tid + st];
        __syncthreads();
    }
    if (tid == 0) {
        atomicAdd(&accg[z], w * (double)red[0]);
        __threadfence();                           // accg visible before done++
        unsigned int d = atomicAdd(done, 1u);
        if (d == (unsigned int)(NJOBS - 1)) {      // last block finalizes
            double kxx = atomicAdd(&accg[0], 0.0); // atomic-RMW read: coherent
            double kyy = atomicAdd(&accg[1], 0.0);
            double kxy = atomicAdd(&accg[2], 0.0);
            const double inv = 1.0 / ((double)NP * (double)NP);
            out[0] = (float)((kxx + kyy - 2.0 * kxy) * inv);
        }
    }
}

extern "C" void kernel_launch(void* const* d_in, const int* in_sizes, int n_in,
                              void* d_out, int out_size, void* d_ws, size_t ws_size,
                              hipStream_t stream) {
    const float* x = (const float*)d_in[0];
    const float* y = (const float*)d_in[1];
    float* out = (float*)d_out;

    char* ws = (char*)d_ws;
    double*       acc  = (double*)ws;                 // [0,24)
    unsigned int* done = (unsigned int*)(ws + 64);    // 4B
    float*  b2f = (float*)(ws + 4096);                // 8KB
    float*  a2f = (float*)(ws + 12288);               // 8KB
    double* d2p = (double*)(ws + 32768);              // 1.5 MB
    unsigned short* Xhi = (unsigned short*)(ws + 32768 + 1605632);
    unsigned short* Yhi = Xhi + (size_t)NP * CD;

    hipMemsetAsync(ws, 0, 20480, stream);             // acc + done + b2f + a2f
    k_prep<<<2304, 256, 0, stream>>>(x, y, d2p, Xhi, a2f);
    k_gather_pack_y<<<dim3(64, 12), 256, 0, stream>>>(y, d2p, Yhi, b2f);
    k_mmd_mfma<<<NJOBS, 256, 0, stream>>>(Xhi, Yhi, a2f, b2f, acc, done, out);
}

// Round 3
// 205.265 us; speedup vs baseline: 1.1154x; 1.0048x over previous
//
#include <hip/hip_runtime.h>

// Problem constants
#define NP 2048          // B*H1*W1 points
#define CD 768           // channels
#define NSPLIT 6         // channel splits for d2 partials (128 ch each)
#define NJOBS 528        // 136 XX-tri + 136 YY-tri + 256 XY tiles
#define MMD_GAMMA 0.00065f

typedef short bf16frag __attribute__((ext_vector_type(8)));
typedef float f32x4 __attribute__((ext_vector_type(4)));
typedef unsigned short u16x4 __attribute__((ext_vector_type(4)));
typedef unsigned short u16x8 __attribute__((ext_vector_type(8)));

#define GLD16(g, l)  __builtin_amdgcn_global_load_lds(                      \
    (const __attribute__((address_space(1))) void*)(g),                     \
    (__attribute__((address_space(3))) void*)(l), 16, 0, 0)

static __device__ inline unsigned short f2bf(float v) {
    union { float f; unsigned u; } a; a.f = v;
    unsigned r = a.u + 0x7fffu + ((a.u >> 16) & 1u);
    return (unsigned short)(r >> 16);
}

// ---------------------------------------------------------------------------
// Fused prep: blocks 0..1535 = d2 partials + bf16 candidate store + per-
// candidate y^2 partials; blocks 1536..2303 = x transpose + bf16 pack + a2.
// d2/argmax math is byte-identical to the passing version.
// Candidate store: during the d2 pass each thread already holds the float4
// of 4 j-candidates -> pack to bf16 via a swizzled 32KB LDS transpose and
// write point-major Ycand[n*16+cand][c]. This kills the second full y read.
__global__ __launch_bounds__(256, 3)
void k_prep(const float* __restrict__ x, const float* __restrict__ y,
            double* __restrict__ d2p,
            unsigned short* __restrict__ Xhi,
            float* __restrict__ a2f,
            unsigned short* __restrict__ Ycand,
            float* __restrict__ b2cand) {
    // union'd shared memory: d2 branch uses 44KB, transpose branch 9.4KB
    __shared__ unsigned long long smem8[45056 / 8];
    unsigned short* ctU   = (unsigned short*)smem8;            // 32 KB: ct[cl][w1s][j]
    double*         redd  = (double*)((char*)smem8 + 32768);   // 8 KB: [8][32][4]
    float*          sqrd2 = (float*)((char*)smem8 + 40960);    // 4 KB: [8][32][4]
    float*          tile  = (float*)smem8;                     // 8.4 KB: [64][33]
    float*          sqred = (float*)((char*)smem8 + 8448);     // 1 KB: [8][32]

    int bid = blockIdx.x;
    int tid = threadIdx.x;

    if (bid < 1536) {
        // ---- d2 partial branch + candidate pack ----
        int bxh = bid & 255;
        int cs  = bid >> 8;
        int b = bxh >> 7, h = bxh & 127;
        int h1 = h >> 2, i = h & 3;
        int w1 = tid & 31, cg = tid >> 5;
        int c0 = cs * 128 + cg;
        const float* yp = y + ((size_t)(b * 768 + c0) * 128 + h) * 128 + 4 * w1;
        const float* xp = x + (size_t)(b * 768 + c0) * 1024 + h1 * 32 + w1;
        double a0 = 0.0, a1 = 0.0, a2 = 0.0, a3 = 0.0;
        float  q0 = 0.f, q1 = 0.f, q2 = 0.f, q3 = 0.f;
        #pragma unroll 8
        for (int k = 0; k < 16; ++k) {
            float4 yv = *(const float4*)yp;
            float xv = *xp;
            // bf16 candidate pack -> LDS (XOR swizzle keeps both phases conflict-free)
            int cl = cg + 8 * k;
            u16x4 pk = { f2bf(yv.x), f2bf(yv.y), f2bf(yv.z), f2bf(yv.w) };
            *(u16x4*)&ctU[cl * 128 + ((w1 ^ (cl & 31)) << 2)] = pk;
            // y^2 partials (f32, matches current b2 quality)
            q0 += yv.x * yv.x; q1 += yv.y * yv.y;
            q2 += yv.z * yv.z; q3 += yv.w * yv.w;
            // d2 partials: UNCHANGED math/order -> argmax bit-identical
            double xd = (double)xv;
            double d0 = xd - (double)yv.x;
            double d1 = xd - (double)yv.y;
            double d2_ = xd - (double)yv.z;
            double d3 = xd - (double)yv.w;
            a0 += d0 * d0; a1 += d1 * d1; a2 += d2_ * d2_; a3 += d3 * d3;
            yp += (size_t)8 * 16384;
            xp += (size_t)8 * 1024;
        }
        {
            int base = (cg * 32 + w1) * 4;
            redd[base + 0] = a0; redd[base + 1] = a1;
            redd[base + 2] = a2; redd[base + 3] = a3;
            sqrd2[base + 0] = q0; sqrd2[base + 1] = q1;
            sqrd2[base + 2] = q2; sqrd2[base + 3] = q3;
        }
        __syncthreads();
        if (tid < 128) {
            int w = tid >> 2, j = tid & 3;
            double s = 0.0;
            #pragma unroll
            for (int g = 0; g < 8; ++g) s += redd[(g * 32 + w) * 4 + j];
            int n = b * 1024 + h1 * 32 + w;
            d2p[((size_t)cs * NP + n) * 16 + i * 4 + j] = s;
        } else {
            int t2 = tid - 128;
            int w = t2 >> 2, j = t2 & 3;
            float s = 0.f;
            #pragma unroll
            for (int g = 0; g < 8; ++g) s += sqrd2[(g * 32 + w) * 4 + j];
            int n = b * 1024 + h1 * 32 + w;
            atomicAdd(&b2cand[(size_t)n * 16 + i * 4 + j], s);
        }
        // ---- candidate readout: 128 (w1,j) rows x 128 channels -> global ----
        {
            int pr = tid & 127, hh = tid >> 7;
            int w1r = pr >> 2, jr = pr & 3;
            size_t n_r = (size_t)(b * 1024 + h1 * 32 + w1r);
            size_t rowbase = (n_r * 16 + (size_t)(i * 4 + jr)) * CD + cs * 128;
            #pragma unroll
            for (int clg2 = 0; clg2 < 8; ++clg2) {
                int cl0 = hh * 64 + clg2 * 8;
                u16x8 v;
                #pragma unroll
                for (int u = 0; u < 8; ++u) {
                    int cl = cl0 + u;
                    v[u] = ctU[cl * 128 + ((w1r ^ (cl & 31)) << 2) + jr];
                }
                *(u16x8*)&Ycand[rowbase + cl0] = v;
            }
        }
    } else {
        // ---- transpose + pack branch (unchanged) ----
        int id = bid - 1536;
        int bx = id & 63;
        int c0 = (id >> 6) * 64;
        int b = bx >> 5, h1 = bx & 31;
        const float* src = x + (size_t)(b * 768 + c0) * 1024 + h1 * 32;
        #pragma unroll
        for (int p = 0; p < 8; ++p) {
            int cl = p * 8 + (tid >> 5);
            int w1 = tid & 31;
            tile[cl * 33 + w1] = src[(size_t)cl * 1024 + w1];
        }
        __syncthreads();
        int n0 = bx * 32;
        #pragma unroll
        for (int p = 0; p < 8; ++p) {
            int w1 = p * 4 + (tid >> 6);
            int c  = tid & 63;
            float v = tile[c * 33 + w1];
            size_t o = (size_t)(n0 + w1) * CD + c0 + c;
            Xhi[o] = f2bf(v);
        }
        {
            int w1 = tid & 31, cseg = tid >> 5;
            float s = 0.f;
            #pragma unroll
            for (int u = 0; u < 8; ++u) {
                float v = tile[(cseg * 8 + u) * 33 + w1];
                s += v * v;
            }
            sqred[cseg * 32 + w1] = s;
        }
        __syncthreads();
        if (tid < 32) {
            float s = 0.f;
            #pragma unroll
            for (int g = 0; g < 8; ++g) s += sqred[g * 32 + tid];
            atomicAdd(&a2f[n0 + tid], s);
        }
    }
}

// ---------------------------------------------------------------------------
// Tiny select: argmax (bit-identical to previous gather) + copy the selected
// 1536B candidate row Ycand -> Yhi, and b2f[n] = b2cand[n*16+bi].
__global__ __launch_bounds__(256, 4)
void k_select(const double* __restrict__ d2p,
              const unsigned short* __restrict__ Ycand,
              const float* __restrict__ b2cand,
              unsigned short* __restrict__ Yhi,
              float* __restrict__ b2f) {
    __shared__ int sBi[32];
    int bh = blockIdx.x;                 // b*32 + h1
    int b = bh >> 5, h1 = bh & 31;
    int tid = threadIdx.x;
    if (tid < 32) {
        int n = b * 1024 + h1 * 32 + tid;
        double s[16];
        #pragma unroll
        for (int k = 0; k < 16; ++k) s[k] = 0.0;
        for (int c = 0; c < NSPLIT; ++c) {
            #pragma unroll
            for (int k = 0; k < 16; ++k) s[k] += d2p[((size_t)c * NP + n) * 16 + k];
        }
        double best = s[0]; int bi = 0;
        #pragma unroll
        for (int k = 1; k < 16; ++k) if (s[k] > best) { best = s[k]; bi = k; }
        sBi[tid] = bi;
        b2f[n] = b2cand[(size_t)n * 16 + bi];
    }
    __syncthreads();
    int n_loc = tid >> 3, c8 = tid & 7;
    int n = b * 1024 + h1 * 32 + n_loc;
    size_t srow = ((size_t)n * 16 + sBi[n_loc]) * CD;
    size_t drow = (size_t)n * CD;
    #pragma unroll
    for (int it = 0; it < 12; ++it) {
        size_t o = (size_t)it * 64 + c8 * 8;
        *(u16x8*)&Yhi[drow + o] = *(const u16x8*)&Ycand[srow + o];
    }
}

// ---------------------------------------------------------------------------
// MFMA Gram + exp-sum, 1-term (Gram = a_hi . b_hi), K=768 as 12 windows of
// K=64; XOR-(r&7) swizzle on 64-short rows. NEW: bijective XCD-aware block
// swizzle (528 = 8*66) so neighboring tiles share an XCD L2.
__global__ __launch_bounds__(256, 3)
void k_mmd_mfma(const unsigned short* __restrict__ Xhi,
                const unsigned short* __restrict__ Yhi,
                const float* __restrict__ a2, const float* __restrict__ b2,
                double* __restrict__ accg, unsigned int* __restrict__ done,
                float* __restrict__ out) {
    __shared__ unsigned short As[128 * 64];   // 16 KB
    __shared__ unsigned short Bs[128 * 64];   // 16 KB
    __shared__ float red[256];

    int bid0 = blockIdx.x;
    int id = (bid0 & 7) * 66 + (bid0 >> 3);   // XCD swizzle, bijective (528=8*66)
    int z, bx, by;
    double w = 1.0;
    if (id < 272) {
        z = (id < 136) ? 0 : 1;
        if (id >= 136) id -= 136;
        int r = 0;
        while (id >= 16 - r) { id -= 16 - r; ++r; }
        by = r; bx = r + id;
        if (bx != by) w = 2.0;
    } else {
        z = 2; id -= 272;
        bx = id & 15; by = id >> 4;
    }
    const unsigned short* AH = (z == 1) ? Yhi : Xhi;
    const unsigned short* BH = (z == 0) ? Xhi : Yhi;
    const float* na = (z == 1) ? b2 : a2;
    const float* nb = (z == 0) ? a2 : b2;
    int i0 = by * 128, j0 = bx * 128;

    int tid = threadIdx.x;
    int lane = tid & 63;
    int wv = tid >> 6;
    int wr = wv >> 1, wc = wv & 1;
    int m = lane & 15, q = lane >> 4;
    int lrow = lane >> 3, lchunk = lane & 7;   // staging: 8 rows x 8 chunks/wave

    f32x4 acc[4][4] = {};

    for (int wnd = 0; wnd < 12; ++wnd) {
        int c0 = wnd * 64;
        __syncthreads();
        #pragma unroll
        for (int s = 0; s < 4; ++s) {
            int r0 = s * 32 + wv * 8;
            int r  = r0 + lrow;
            int cg = lchunk ^ (r & 7);
            GLD16(AH + (size_t)(i0 + r) * CD + c0 + cg * 8, &As[r0 * 64]);
        }
        #pragma unroll
        for (int s = 0; s < 4; ++s) {
            int r0 = s * 32 + wv * 8;
            int r  = r0 + lrow;
            int cg = lchunk ^ (r & 7);
            GLD16(BH + (size_t)(j0 + r) * CD + c0 + cg * 8, &Bs[r0 * 64]);
        }
        __syncthreads();
        #pragma unroll
        for (int kh = 0; kh < 2; ++kh) {      // two K=32 halves of the window
            bf16frag af[4], bg[4];
            #pragma unroll
            for (int t = 0; t < 4; ++t) {
                int ra = wr * 64 + t * 16 + m;
                af[t] = *(const bf16frag*)&As[ra * 64 + ((kh * 4 + q) ^ (ra & 7)) * 8];
            }
            #pragma unroll
            for (int t = 0; t < 4; ++t) {
                int rb = wc * 64 + t * 16 + m;
                bg[t] = *(const bf16frag*)&Bs[rb * 64 + ((kh * 4 + q) ^ (rb & 7)) * 8];
            }
            #pragma unroll
            for (int ti = 0; ti < 4; ++ti)
                #pragma unroll
                for (int tj = 0; tj < 4; ++tj)
                    acc[ti][tj] = __builtin_amdgcn_mfma_f32_16x16x32_bf16(
                        af[ti], bg[tj], acc[ti][tj], 0, 0, 0);
        }
    }

    float s = 0.0f;
    #pragma unroll
    for (int ti = 0; ti < 4; ++ti) {
        #pragma unroll
        for (int r = 0; r < 4; ++r) {
            int i = i0 + wr * 64 + ti * 16 + q * 4 + r;
            float ai = na[i];
            #pragma unroll
            for (int tj = 0; tj < 4; ++tj) {
                int j = j0 + wc * 64 + tj * 16 + m;
                float d = ai + nb[j] - 2.0f * acc[ti][tj][r];
                d = fmaxf(d, 0.0f);
                s += expf(-MMD_GAMMA * d);
            }
        }
    }
    red[tid] = s;
    __syncthreads();
    for (int st = 128; st > 0; st >>= 1) {
        if (tid < st) red[tid] += red[tid + st];
        __syncthreads();
    }
    if (tid == 0) {
        atomicAdd(&accg[z], w * (double)red[0]);
        __threadfence();                           // accg visible before done++
        unsigned int d = atomicAdd(done, 1u);
        if (d == (unsigned int)(NJOBS - 1)) {      // last block finalizes
            double kxx = atomicAdd(&accg[0], 0.0); // atomic-RMW read: coherent
            double kyy = atomicAdd(&accg[1], 0.0);
            double kxy = atomicAdd(&accg[2], 0.0);
            const double inv = 1.0 / ((double)NP * (double)NP);
            out[0] = (float)((kxx + kyy - 2.0 * kxy) * inv);
        }
    }
}

extern "C" void kernel_launch(void* const* d_in, const int* in_sizes, int n_in,
                              void* d_out, int out_size, void* d_ws, size_t ws_size,
                              hipStream_t stream) {
    const float* x = (const float*)d_in[0];
    const float* y = (const float*)d_in[1];
    float* out = (float*)d_out;

    char* ws = (char*)d_ws;
    double*       acc    = (double*)ws;                  // [0,24)
    unsigned int* done   = (unsigned int*)(ws + 64);     // 4B
    float*  b2f    = (float*)(ws + 4096);                // 8KB
    float*  a2f    = (float*)(ws + 12288);               // 8KB
    float*  b2cand = (float*)(ws + 20480);               // 128KB -> ends 151552
    double* d2p    = (double*)(ws + 151552);             // 1.5MB -> ends 1724416
    unsigned short* Xhi   = (unsigned short*)(ws + 1724416);          // 3.0MB
    unsigned short* Yhi   = (unsigned short*)(ws + 4870144);          // 3.0MB
    unsigned short* Ycand = (unsigned short*)(ws + 8015872);          // 48MB

    hipMemsetAsync(ws, 0, 151552, stream);   // acc + done + b2f + a2f + b2cand
    k_prep<<<2304, 256, 0, stream>>>(x, y, d2p, Xhi, a2f, Ycand, b2cand);
    k_select<<<64, 256, 0, stream>>>(d2p, Ycand, b2cand, Yhi, b2f);
    k_mmd_mfma<<<NJOBS, 256, 0, stream>>>(Xhi, Yhi, a2f, b2f, acc, done, out);
}